// Round 2
// baseline (375.477 us; speedup 1.0000x reference)
//
#include <hip/hip_runtime.h>

// FlaxLinear irrep-wise linear: out[b, xoff + w*d + i] = PW * sum_u x[b, xoff + u*d + i] * W[u,w]  (+b0 for d=1)
// Channels: d=1 (xoff 0, w0), d=3 (xoff 512, w1), d=5 (xoff 2048, w2).
// One block = 64 rows x 64 w-cols x ALL d irreps; d compute-waves, one irrep plane each.
// Staging: thread loads 4*d CONSECUTIVE floats -> contains 4 same-irrep elems at k..k+3
//          -> one packed ds_write_b64 per irrep. No strided global access anywhere.
// Epilogue (d>1): C through LDS (gcd(d,32)=1 -> conflict-free) -> contiguous global rows.

#define DTOT 4608
#define NMUL 512
#define BK 32
#define LDA 40                 // shorts per LDS row (80B: 16B-aligned, 2-way banks = free)
#define APLANE (64 * LDA)      // 2560 shorts per plane
#define NTHR 320               // 5 waves

typedef __attribute__((ext_vector_type(8))) short short8;
typedef __attribute__((ext_vector_type(4))) float float4v;

__device__ __forceinline__ unsigned int fbits(float f) {
    return __builtin_bit_cast(unsigned int, f);
}

template <int D>
__device__ __forceinline__ void gemm_body(
    int rel, const float* __restrict__ x, const float* __restrict__ W,
    const float* __restrict__ b0, float* __restrict__ out,
    unsigned short* As, unsigned short* Bs, float* Cs)
{
    constexpr int P      = (D == 1) ? 4 : D;     // planes = compute waves
    constexpr int ROWS   = (D == 1) ? 256 : 64;  // rows per block
    constexpr int XOFF   = (D == 1) ? 0 : (D == 3 ? 512 : 2048);
    constexpr int NCHUNK = ROWS * 8;             // chunks per K-step; chunk = 4*D floats

    const int tid  = threadIdx.x;
    const int lane = tid & 63;
    const int w    = tid >> 6;       // wave id 0..4
    const int lr   = lane & 15;
    const int lq   = lane >> 4;

    const int nt = rel & 7;
    const int mt = rel >> 3;
    const int n0 = nt * 64;
    const int m0 = mt * ROWS;

    const int bn  = tid & 63;        // B staging: lane-consecutive n
    const int bk0 = tid >> 6;

    float4v acc[4][4];
#pragma unroll
    for (int a = 0; a < 4; ++a)
#pragma unroll
        for (int b = 0; b < 4; ++b) acc[a][b] = (float4v)0.f;

    for (int kt = 0; kt < NMUL / BK; ++kt) {
        // ---- A staging: contiguous 4*D-float chunks, packed b64 writes per irrep ----
        for (int c = tid; c < NCHUNK; c += NTHR) {
            const int row = c >> 3;
            const int j   = c & 7;   // k-quad within BK: k = j*4 .. j*4+3
            const float* src = x + (size_t)(m0 + row) * DTOT + XOFF + (kt * BK + j * 4) * D;
            float4v f[D];
#pragma unroll
            for (int q = 0; q < D; ++q) f[q] = *(const float4v*)(src + q * 4);
            const int rin   = (D == 1) ? (row & 63) : row;
            const int pbase = (D == 1) ? (row >> 6) : 0;
#pragma unroll
            for (int i = 0; i < D; ++i) {
                const int pl = (D == 1) ? pbase : i;
                // same-irrep elements sit at chunk positions i, i+D, i+2D, i+3D -> k = 4j..4j+3
                unsigned int u0 = fbits(f[(i + 0 * D) >> 2][(i + 0 * D) & 3]) + 0x8000u;
                unsigned int u1 = fbits(f[(i + 1 * D) >> 2][(i + 1 * D) & 3]) + 0x8000u;
                unsigned int u2 = fbits(f[(i + 2 * D) >> 2][(i + 2 * D) & 3]) + 0x8000u;
                unsigned int u3 = fbits(f[(i + 3 * D) >> 2][(i + 3 * D) & 3]) + 0x8000u;
                uint2 pk;
                pk.x = __builtin_amdgcn_perm(u1, u0, 0x07060302u);  // [bf16(u0) | bf16(u1)<<16]
                pk.y = __builtin_amdgcn_perm(u3, u2, 0x07060302u);
                *(uint2*)(As + pl * APLANE + rin * LDA + j * 4) = pk;
            }
        }
        // ---- B staging: Bs[n][k] = W[kt*32+k][n0+n]; lanes consecutive in n (2-way banks) ----
        for (int k = bk0; k < BK; k += NTHR / 64) {
            const float v = W[(size_t)(kt * BK + k) * NMUL + n0 + bn];
            Bs[bn * LDA + k] = (unsigned short)((fbits(v) + 0x8000u) >> 16);
        }
        __syncthreads();

        // ---- MFMA: wave w computes its plane's 64x64 tile (4x4 of 16x16x32) ----
        if (w < P) {
            const unsigned short* Ap = As + w * APLANE;
            short8 afr[4], bfr[4];
#pragma unroll
            for (int mi = 0; mi < 4; ++mi)
                afr[mi] = *(const short8*)(Ap + (mi * 16 + lr) * LDA + lq * 8);
#pragma unroll
            for (int ni = 0; ni < 4; ++ni)
                bfr[ni] = *(const short8*)(Bs + (ni * 16 + lr) * LDA + lq * 8);
#pragma unroll
            for (int mi = 0; mi < 4; ++mi)
#pragma unroll
                for (int ni = 0; ni < 4; ++ni)
                    acc[mi][ni] = __builtin_amdgcn_mfma_f32_16x16x32_bf16(
                        afr[mi], bfr[ni], acc[mi][ni], 0, 0, 0);
        }
        __syncthreads();
    }

    const float PW = 0.044194173824159216f;  // 512^-0.5
    if (D == 1) {
        // direct stores are already coalesced (cols contiguous)
        if (w < P) {
#pragma unroll
            for (int ni = 0; ni < 4; ++ni) {
                const int col = n0 + ni * 16 + lr;
                const float bias = b0[col];
#pragma unroll
                for (int mi = 0; mi < 4; ++mi)
#pragma unroll
                    for (int r = 0; r < 4; ++r)
                        out[(size_t)(m0 + w * 64 + mi * 16 + lq * 4 + r) * DTOT + col] =
                            acc[mi][ni][r] * PW + bias;
            }
        }
    } else {
        // route C through LDS to produce contiguous 64*D-float output rows
#pragma unroll
        for (int mc = 0; mc < 4; ++mc) {
            if (w < P) {
#pragma unroll
                for (int ni = 0; ni < 4; ++ni)
#pragma unroll
                    for (int r = 0; r < 4; ++r)
                        Cs[(lq * 4 + r) * (64 * D) + (ni * 16 + lr) * D + w] =
                            acc[mc][ni][r] * PW;
            }
            __syncthreads();
            constexpr int F4 = 16 * 16 * D;  // float4s per 16-row chunk
            for (int f = tid; f < F4; f += NTHR) {
                const int row = f / (16 * D);
                const int c4  = f % (16 * D);
                *(float4v*)(out + (size_t)(m0 + mc * 16 + row) * DTOT + XOFF + n0 * D + c4 * 4) =
                    *(const float4v*)(Cs + f * 4);
            }
            __syncthreads();
        }
    }
}

__global__ __launch_bounds__(NTHR) void flax_linear_kernel(
    const float* __restrict__ x, const float* __restrict__ w0,
    const float* __restrict__ w1, const float* __restrict__ w2,
    const float* __restrict__ b0, float* __restrict__ out)
{
    __shared__ __align__(16) unsigned char smem[25600];   // As (<=5 planes) / Cs (epilogue) union
    __shared__ __align__(16) unsigned short Bs[64 * LDA]; // 5.1 KB
    unsigned short* As = (unsigned short*)smem;
    float* Cs = (float*)smem;

    const int b = blockIdx.x;
    if (b < 512)       gemm_body<5>(b, x, w2, b0, out, As, Bs, Cs);         // heaviest first
    else if (b < 1024) gemm_body<3>(b - 512, x, w1, b0, out, As, Bs, Cs);
    else               gemm_body<1>(b - 1024, x, w0, b0, out, As, Bs, Cs);
}

extern "C" void kernel_launch(void* const* d_in, const int* in_sizes, int n_in,
                              void* d_out, int out_size, void* d_ws, size_t ws_size,
                              hipStream_t stream) {
    const float* x  = (const float*)d_in[0];
    const float* w0 = (const float*)d_in[1];
    const float* w1 = (const float*)d_in[2];
    const float* w2 = (const float*)d_in[3];
    const float* b0 = (const float*)d_in[4];
    float* out = (float*)d_out;

    // d=5: 512 blocks (64 m x 8 n), d=3: 512, d=1: 128 (16 m x 8 n)
    flax_linear_kernel<<<dim3(1152), dim3(NTHR), 0, stream>>>(x, w0, w1, w2, b0, out);
}